// Round 21
// baseline (385.740 us; speedup 1.0000x reference)
//
#include <hip/hip_runtime.h>
#include <hip/hip_bf16.h>

// USM sharpen, SINGLE-dispatch: R20 pass bodies (91.6us, verified) + software
// grid barrier. 768 blocks = EXACTLY 3/CU (LDS 52224 -> 3/CU; launch_bounds
// (512,6) caps VGPR<=85) -> all blocks co-resident -> atomic-counter barrier
// cannot deadlock. Each block: K1 on 2 tiles, barrier, K2 on the same 2 tiles
// (L2-warm img/res). Cooperative launch is unsupported here (R17) -> manual.
// Cross-XCD coherence (G16): per-XCD L2s are not flushed mid-kernel, so ALL
// res accesses use agent-scope atomics (cache-bypass to the coherent point):
// K1 res stores, K2 halo stage loads (b64), K2 center loads (b16).
// __threadfence + ACQ_REL counter = ordering. img read-only; out written once.
// Tile body = R20 verbatim: 64x128 tile, stage st[192][136p] bf16 (y=y0-33+s,
// s<186 data+clamp), H[64][200p] aliased at st base, phase-C accs in regs,
// 2 K-slices + g-predicated exact tap corrections, R7 fragment convention,
// K1 epilogue img center from staged LDS copy, bijective XCD swizzle.

typedef __attribute__((ext_vector_type(8))) short bf16x8;
typedef __attribute__((ext_vector_type(4))) float f32x4;

constexpr int IMG = 512, NIMG = 48, K = 51;
constexpr int SP = 136;      // stage pitch (68 dwords == 4 mod 32)
constexpr int YP = 200;      // H pitch (100 dwords == 4 mod 32)
constexpr int SROWS = 192;   // staged row slots
constexpr int SDATA = 186;   // real data rows (33 + 128 + 25)
constexpr int NBLK = 768;    // 3 blocks/CU x 256 CUs

__device__ __forceinline__ float bf2f(unsigned short u) {
    return __builtin_bit_cast(float, (unsigned)u << 16);
}
__device__ __forceinline__ unsigned short f2bf(float f) {
    unsigned u = __builtin_bit_cast(unsigned, f);
    u += 0x7FFF + ((u >> 16) & 1);  // RNE, finite inputs only
    return (unsigned short)(u >> 16);
}
__device__ __forceinline__ int refl(int i) {
    i = i < 0 ? -i : i;
    return i >= IMG ? 2 * IMG - 2 - i : i;
}
// agent-scope (cross-XCD coherent) res accessors
__device__ __forceinline__ unsigned long long aload64(const unsigned short* p) {
    return __hip_atomic_load((const unsigned long long*)p, __ATOMIC_RELAXED,
                             __HIP_MEMORY_SCOPE_AGENT);
}
__device__ __forceinline__ unsigned short aload16(const unsigned short* p) {
    return __hip_atomic_load(p, __ATOMIC_RELAXED, __HIP_MEMORY_SCOPE_AGENT);
}
__device__ __forceinline__ void astore16(unsigned short* p, unsigned short v) {
    __hip_atomic_store(p, v, __ATOMIC_RELAXED, __HIP_MEMORY_SCOPE_AGENT);
}

struct Bands {
    bf16x8 a_v[2], a_h[2];
    float gg0, gg49, gg50;
};

template <int PASS>  // 0: img -> res ; 1: res -> out
__device__ __forceinline__ void do_tile(unsigned short* st, const Bands& W, int sw,
                                        const float* __restrict__ img,
                                        unsigned short* __restrict__ resbuf,
                                        float* __restrict__ out,
                                        int tid, int wv, int m16, int g) {
    unsigned short* const Hl = st;  // H[64][YP] aliases st base
    const int bz = sw >> 5, r5 = sw & 31, byy = r5 >> 3, bxx = r5 & 7;
    const int x0 = bxx * 64, y0 = byy * 128;
    const size_t base = (size_t)bz * (IMG * IMG);
    const float* __restrict__ imgb = img + base;
    unsigned short* __restrict__ resb = resbuf + base;
    float* __restrict__ outb = out + base;

    // ---- stage 192 row-slots x 128 cols (row-dense b128 writes) ----
    const bool xedge = (bxx == 0) | (bxx == 7);
    const int r0t = tid >> 4, c8 = (tid & 15) * 8;
#pragma unroll
    for (int j = 0; j < 6; ++j) {
        const int s = r0t + 32 * j;
        const int rowo = refl(y0 - 33 + min(s, SDATA - 1)) * IMG + (x0 - 32 + c8);
        unsigned pk[4];
        if (PASS == 0) {
            float v[8];
            if (!xedge) {
                const f32x4 f0 = *(const f32x4*)&imgb[rowo];
                const f32x4 f1 = *(const f32x4*)&imgb[rowo + 4];
#pragma unroll
                for (int e = 0; e < 4; ++e) { v[e] = f0[e]; v[e + 4] = f1[e]; }
            } else {
                const int rb = rowo - (x0 - 32 + c8);
#pragma unroll
                for (int e = 0; e < 8; ++e) v[e] = imgb[rb + refl(x0 - 32 + c8 + e)];
            }
#pragma unroll
            for (int w = 0; w < 4; ++w)
                pk[w] = (unsigned)f2bf(v[2 * w]) | ((unsigned)f2bf(v[2 * w + 1]) << 16);
        } else {
            unsigned rw[4];
            if (!xedge) {
                const unsigned long long q0 = aload64(&resb[rowo]);      // agent b64
                const unsigned long long q1 = aload64(&resb[rowo + 4]);
                rw[0] = (unsigned)q0; rw[1] = (unsigned)(q0 >> 32);
                rw[2] = (unsigned)q1; rw[3] = (unsigned)(q1 >> 32);
            } else {
                const int rb = rowo - (x0 - 32 + c8);
#pragma unroll
                for (int w = 0; w < 4; ++w) {
                    const unsigned short e0 = aload16(&resb[rb + refl(x0 - 32 + c8 + 2 * w)]);
                    const unsigned short e1 = aload16(&resb[rb + refl(x0 - 32 + c8 + 2 * w + 1)]);
                    rw[w] = (unsigned)e0 | ((unsigned)e1 << 16);
                }
            }
#pragma unroll
            for (int w = 0; w < 4; ++w) {  // mask(|res|*255>10): exact bf16 bit-compare
                const unsigned lo = ((rw[w] & 0x7FFFu) > 0x3D20u) ? 0x3F80u : 0u;
                const unsigned hi = (((rw[w] >> 16) & 0x7FFFu) > 0x3D20u) ? 0x3F80u : 0u;
                pk[w] = lo | (hi << 16);
            }
        }
        *(uint4*)&st[s * SP + c8] = make_uint4(pk[0], pk[1], pk[2], pk[3]);
    }
    __syncthreads();

    // ---- phase C: hblur, 48 tiles (4 xs x 12 yt), 6/wave, accs in regs ----
    f32x4 cacc[6];
#pragma unroll
    for (int k6 = 0; k6 < 6; ++k6) {
        const int t = wv + 8 * k6;
        const int xs = t & 3, yt = t >> 2;
        const int n = 16 * yt + m16;  // B col = stage row s
        f32x4 acc = {0.f, 0.f, 0.f, 0.f};
#pragma unroll
        for (int rs = 0; rs < 2; ++rs) {
            const bf16x8 b = *(const bf16x8*)&st[n * SP + 16 * xs + 8 + 32 * rs + 8 * g];
            acc = __builtin_amdgcn_mfma_f32_16x16x32_bf16(W.a_h[rs], b, acc, 0, 0, 0);
        }
        if (g == 0) acc[0] = fmaf(W.gg0,  bf2f(st[n * SP + 16 * xs + 7]),  acc[0]);  // i=0,  t=0
        if (g == 3) acc[3] = fmaf(W.gg50, bf2f(st[n * SP + 16 * xs + 72]), acc[3]);  // i=15, t=50
        cacc[k6] = acc;
    }

    // ---- K1: save img center (staged bf16) to regs before the alias clobber ----
    unsigned short civ[4][4];
    if (PASS == 0) {
#pragma unroll
        for (int k4 = 0; k4 < 4; ++k4) {
            const int t = wv + 8 * k4;
            const int xs2 = t & 3, ys = t >> 2;
            const int xl = 16 * xs2 + m16;
#pragma unroll
            for (int q = 0; q < 4; ++q)
                civ[k4][q] = st[(33 + 16 * ys + 4 * g + q) * SP + xl + 32];
        }
    }
    __syncthreads();  // st fully consumed; H may overwrite its base

    // ---- H write (aliased into st) ----
#pragma unroll
    for (int k6 = 0; k6 < 6; ++k6) {
        const int t = wv + 8 * k6;
        const int xs = t & 3, yt = t >> 2;
        const int n = 16 * yt + m16;
#pragma unroll
        for (int q = 0; q < 4; ++q)
            Hl[(16 * xs + 4 * g + q) * YP + n] = f2bf(cacc[k6][q]);
    }
    __syncthreads();

    // ---- phase D: vblur + fused epilogue, 32 tiles (4 x 8), 4/wave ----
#pragma unroll
    for (int k4 = 0; k4 < 4; ++k4) {
        const int t = wv + 8 * k4;
        const int xs2 = t & 3, ys = t >> 2;
        const int xl = 16 * xs2 + m16;
        f32x4 acc = {0.f, 0.f, 0.f, 0.f};
#pragma unroll
        for (int rs = 0; rs < 2; ++rs) {
            const bf16x8 b = *(const bf16x8*)&Hl[xl * YP + 16 * ys + 8 + 32 * rs + 8 * g];
            acc = __builtin_amdgcn_mfma_f32_16x16x32_bf16(W.a_v[rs], b, acc, 0, 0, 0);
        }
        if (g == 3) {
            const float h72 = bf2f(Hl[xl * YP + 16 * ys + 72]);
            const float h73 = bf2f(Hl[xl * YP + 16 * ys + 73]);
            acc[2] = fmaf(W.gg50, h72, acc[2]);                     // i=14, t=50
            acc[3] = fmaf(W.gg49, h72, fmaf(W.gg50, h73, acc[3]));  // i=15, t=49,50
        }
        const int yl0 = 16 * ys + 4 * g;
#pragma unroll
        for (int q = 0; q < 4; ++q) {
            const int di = (y0 + yl0 + q) * IMG + (x0 + xl);
            if (PASS == 0) {
                const float iv = bf2f(civ[k4][q]);   // staged img center
                astore16(&resb[di], f2bf(iv - acc[q]));
            } else {
                const float iv = imgb[di];           // L2-hot (same block staged it)
                const float rv = bf2f(aload16(&resb[di]));
                float sharp = fmaf(0.5f, rv, iv);
                sharp = fminf(fmaxf(sharp, 0.f), 1.f);
                outb[di] = fmaf(acc[q], sharp - iv, iv);  // img + sm*(sharp-img)
            }
        }
    }
    __syncthreads();  // Hl readers done before next tile's stage overwrites st
}

__global__ __launch_bounds__(512, 6) void usm_merged(const float* __restrict__ img,
                                                     unsigned short* __restrict__ resbuf,
                                                     float* __restrict__ out,
                                                     const float* __restrict__ k1d,
                                                     unsigned* __restrict__ ctr) {
    __shared__ unsigned short st[SROWS * SP];  // 52224 B; H aliases its base

    const int tid = threadIdx.x, lane = tid & 63;
    const int wv = __builtin_amdgcn_readfirstlane(tid >> 6);
    const int m16 = lane & 15, g = lane >> 4;
    const int b = blockIdx.x;

    // ---- W bands in registers: a_v[rs][j]=g[32rs+8g+j-m16], a_h = idx+1 ----
    Bands W;
#pragma unroll
    for (int rs = 0; rs < 2; ++rs) {
        float gt[9];
#pragma unroll
        for (int e = 0; e < 9; ++e) {
            const int t = 32 * rs + 8 * g + e - m16;
            gt[e] = ((unsigned)t < (unsigned)K) ? k1d[t] : 0.f;
        }
#pragma unroll
        for (int j = 0; j < 8; ++j) {
            W.a_v[rs][j] = (short)f2bf(gt[j]);
            W.a_h[rs][j] = (short)f2bf(gt[j + 1]);
        }
    }
    W.gg0 = k1d[0]; W.gg49 = k1d[49]; W.gg50 = k1d[50];

    // ---- phase 1: K1 on 2 tiles (ids b and b+768, R20 swizzle) ----
#pragma unroll 1
    for (int tt = 0; tt < 2; ++tt) {
        const int id = b + NBLK * tt;
        const int sw = (id & 7) * 192 + (id >> 3);  // bijective: 1536 = 8*192
        do_tile<0>(st, W, sw, img, resbuf, out, tid, wv, m16, g);
    }

    // ---- software grid barrier (all 768 blocks co-resident by construction) ----
    __threadfence();   // drain this thread's res stores to the coherent point
    __syncthreads();
    if (tid == 0) {
        __hip_atomic_fetch_add(ctr, 1u, __ATOMIC_ACQ_REL, __HIP_MEMORY_SCOPE_AGENT);
        while (__hip_atomic_load(ctr, __ATOMIC_ACQUIRE, __HIP_MEMORY_SCOPE_AGENT) < NBLK)
            __builtin_amdgcn_s_sleep(32);
    }
    __syncthreads();

    // ---- phase 2: K2 on the same 2 tiles (L2-warm img) ----
#pragma unroll 1
    for (int tt = 0; tt < 2; ++tt) {
        const int id = b + NBLK * tt;
        const int sw = (id & 7) * 192 + (id >> 3);
        do_tile<1>(st, W, sw, img, resbuf, out, tid, wv, m16, g);
    }
}

extern "C" void kernel_launch(void* const* d_in, const int* in_sizes, int n_in,
                              void* d_out, int out_size, void* d_ws, size_t ws_size,
                              hipStream_t stream) {
    (void)in_sizes; (void)n_in; (void)out_size; (void)ws_size;
    const float* img = (const float*)d_in[0];
    const float* k1d = (const float*)d_in[1];
    float* out = (float*)d_out;
    unsigned short* rs = (unsigned short*)d_ws;                       // 25165824 B
    unsigned* ctr = (unsigned*)((char*)d_ws + 25165824);              // 4 B counter

    hipMemsetAsync(ctr, 0, 4, stream);  // reset barrier counter (capturable)
    usm_merged<<<dim3(NBLK), 512, 0, stream>>>(img, rs, out, k1d, ctr);
}

// Round 22
// 91.758 us; speedup vs baseline: 4.2039x; 4.2039x over previous
//
#include <hip/hip_runtime.h>
#include <hip/hip_bf16.h>

// USM sharpen, fused 2-kernel MFMA — R20 champion (91.6us), restored verbatim
// after the R21 merged-dispatch experiment regressed 4.2x (agent-scope atomics
// bypass L2 on every res access; in-kernel grid barrier serializes on the
// slowest block; cooperative launch unsupported in this harness per R17).
//   K1 (PASS 0): img f32 --[hblur -> H(LDS alias) -> vblur]--> res bf16
//   K2 (PASS 1): mask(res) --[hblur -> H -> vblur]--> sm; out = img + sm*(sharp-img)
// Geometry: tall 64(x)x128(y) tiles, 1536 blocks (halo amplification 2.9 vs
// 4.0 at 64x64 -- the one lever that won, R19->R20). Stage st[192 rows][136p]
// bf16 row-major (y = y0-33+s, s<186 data, 186..191 clamp-filled finite;
// x = x0-32+c, c in [0,128)). H[64 x'][200p s] aliased at st base (pitch 200
// = 100 dwords == 4 mod 32, same bank residue as the stage pitch). Phase C:
// 48 MFMA tiles (4 xs x 12 yt), 6/wave, accumulators in regs across the alias
// barrier. Phase D: 32 tiles (4 x 8), 4/wave. 2 K-slices + g-predicated exact
// tap corrections (hblur: i=0/t=0 @c=16xs+7, i=15/t=50 @c=16xs+72; vblur:
// i=14/t=50 @s=16ys+72, i=15/t=49,50 @s=16ys+72,73). R7 fragment convention.
// K1 epilogue reads img center from the staged LDS copy (saved to regs before
// the alias clobber) -- no 50 MB global re-read. Mask via exact bf16
// bit-compare (u&0x7FFF)>0x3D20 <=> |res|*255>10. Bijective chunked XCD
// swizzle (1536 = 8*192). LDS 52224 B -> 3 blocks/CU.
// Session ledger: 168 (R1) -> 120 (R3) -> 101 (R5) -> 96.4 (R13) -> 91.6 (R20).
// Profile at 91.6: VALU 24%, MFMA 2.5%, HBM 12% -- latency-structural plateau,
// not a throughput roofline; remaining levers (coop grid sync, cross-XCD
// coherent merge) are unavailable/net-negative on this stack.

typedef __attribute__((ext_vector_type(8))) short bf16x8;
typedef __attribute__((ext_vector_type(4))) float f32x4;

constexpr int IMG = 512, NIMG = 48, K = 51;
constexpr int SP = 136;      // stage pitch (68 dwords == 4 mod 32)
constexpr int YP = 200;      // H pitch (100 dwords == 4 mod 32)
constexpr int SROWS = 192;   // staged row slots
constexpr int SDATA = 186;   // real data rows (33 + 128 + 25)

__device__ __forceinline__ float bf2f(unsigned short u) {
    return __builtin_bit_cast(float, (unsigned)u << 16);
}
__device__ __forceinline__ unsigned short f2bf(float f) {
    unsigned u = __builtin_bit_cast(unsigned, f);
    u += 0x7FFF + ((u >> 16) & 1);  // RNE, finite inputs only
    return (unsigned short)(u >> 16);
}
__device__ __forceinline__ int refl(int i) {
    i = i < 0 ? -i : i;
    return i >= IMG ? 2 * IMG - 2 - i : i;
}

template <int PASS>  // 0: img -> res ; 1: res -> out
__global__ __launch_bounds__(512, 6) void usm_kern(const float* __restrict__ img,
                                                   unsigned short* __restrict__ resbuf,
                                                   float* __restrict__ out,
                                                   const float* __restrict__ k1d) {
    __shared__ unsigned short st[SROWS * SP];      // 52224 B; H aliases its base
    unsigned short* const Hl = st;                 // H[64][YP] = 25600 shorts < st

    const int tid = threadIdx.x, lane = tid & 63;
    const int wv = __builtin_amdgcn_readfirstlane(tid >> 6);
    const int m16 = lane & 15, g = lane >> 4;

    const int id = blockIdx.x;
    const int sw = (id & 7) * 192 + (id >> 3);  // bijective XCD swizzle: 1536 = 8*192
    const int bz = sw >> 5, r5 = sw & 31, byy = r5 >> 3, bxx = r5 & 7;
    const int x0 = bxx * 64, y0 = byy * 128;
    const size_t base = (size_t)bz * (IMG * IMG);
    const float* __restrict__ imgb = img + base;
    unsigned short* __restrict__ resb = resbuf + base;
    float* __restrict__ outb = out + base;

    // ---- W bands in registers: a_v[rs][j]=g[32rs+8g+j-m16], a_h = idx+1 ----
    bf16x8 a_v[2], a_h[2];
#pragma unroll
    for (int rs = 0; rs < 2; ++rs) {
        float gt[9];
#pragma unroll
        for (int e = 0; e < 9; ++e) {
            const int t = 32 * rs + 8 * g + e - m16;
            gt[e] = ((unsigned)t < (unsigned)K) ? k1d[t] : 0.f;
        }
#pragma unroll
        for (int j = 0; j < 8; ++j) {
            a_v[rs][j] = (short)f2bf(gt[j]);
            a_h[rs][j] = (short)f2bf(gt[j + 1]);
        }
    }
    const float gg0 = k1d[0], gg49 = k1d[49], gg50 = k1d[50];  // uniform -> SGPR

    // ---- stage 192 row-slots x 128 cols (row-dense b128 writes) ----
    const bool xedge = (bxx == 0) | (bxx == 7);
    const int r0t = tid >> 4, c8 = (tid & 15) * 8;
#pragma unroll
    for (int j = 0; j < 6; ++j) {
        const int s = r0t + 32 * j;
        const int rowo = refl(y0 - 33 + min(s, SDATA - 1)) * IMG + (x0 - 32 + c8);
        unsigned pk[4];
        if (PASS == 0) {
            float v[8];
            if (!xedge) {
                const f32x4 f0 = *(const f32x4*)&imgb[rowo];
                const f32x4 f1 = *(const f32x4*)&imgb[rowo + 4];
#pragma unroll
                for (int e = 0; e < 4; ++e) { v[e] = f0[e]; v[e + 4] = f1[e]; }
            } else {
                const int rb = rowo - (x0 - 32 + c8);
#pragma unroll
                for (int e = 0; e < 8; ++e) v[e] = imgb[rb + refl(x0 - 32 + c8 + e)];
            }
#pragma unroll
            for (int w = 0; w < 4; ++w)
                pk[w] = (unsigned)f2bf(v[2 * w]) | ((unsigned)f2bf(v[2 * w + 1]) << 16);
        } else {
            unsigned rw[4];
            if (!xedge) {
                const uint4 q4 = *(const uint4*)&resb[rowo];
                rw[0] = q4.x; rw[1] = q4.y; rw[2] = q4.z; rw[3] = q4.w;
            } else {
                const int rb = rowo - (x0 - 32 + c8);
#pragma unroll
                for (int w = 0; w < 4; ++w) {
                    const unsigned short e0 = resb[rb + refl(x0 - 32 + c8 + 2 * w)];
                    const unsigned short e1 = resb[rb + refl(x0 - 32 + c8 + 2 * w + 1)];
                    rw[w] = (unsigned)e0 | ((unsigned)e1 << 16);
                }
            }
#pragma unroll
            for (int w = 0; w < 4; ++w) {  // mask(|res|*255>10): exact bf16 bit-compare
                const unsigned lo = ((rw[w] & 0x7FFFu) > 0x3D20u) ? 0x3F80u : 0u;
                const unsigned hi = (((rw[w] >> 16) & 0x7FFFu) > 0x3D20u) ? 0x3F80u : 0u;
                pk[w] = lo | (hi << 16);
            }
        }
        *(uint4*)&st[s * SP + c8] = make_uint4(pk[0], pk[1], pk[2], pk[3]);
    }
    __syncthreads();

    // ---- phase C: hblur, 48 tiles (4 xs x 12 yt), 6/wave, accs in regs ----
    f32x4 cacc[6];
#pragma unroll
    for (int k6 = 0; k6 < 6; ++k6) {
        const int t = wv + 8 * k6;
        const int xs = t & 3, yt = t >> 2;
        const int n = 16 * yt + m16;  // B col = stage row s
        f32x4 acc = {0.f, 0.f, 0.f, 0.f};
#pragma unroll
        for (int rs = 0; rs < 2; ++rs) {
            const bf16x8 b = *(const bf16x8*)&st[n * SP + 16 * xs + 8 + 32 * rs + 8 * g];
            acc = __builtin_amdgcn_mfma_f32_16x16x32_bf16(a_h[rs], b, acc, 0, 0, 0);
        }
        if (g == 0) acc[0] = fmaf(gg0,  bf2f(st[n * SP + 16 * xs + 7]),  acc[0]);  // i=0,  t=0
        if (g == 3) acc[3] = fmaf(gg50, bf2f(st[n * SP + 16 * xs + 72]), acc[3]);  // i=15, t=50
        cacc[k6] = acc;
    }

    // ---- K1: save img center (staged bf16) to regs before the alias clobber ----
    unsigned short civ[4][4];
    if (PASS == 0) {
#pragma unroll
        for (int k4 = 0; k4 < 4; ++k4) {
            const int t = wv + 8 * k4;
            const int xs2 = t & 3, ys = t >> 2;
            const int xl = 16 * xs2 + m16;
#pragma unroll
            for (int q = 0; q < 4; ++q)
                civ[k4][q] = st[(33 + 16 * ys + 4 * g + q) * SP + xl + 32];
        }
    }
    __syncthreads();  // st fully consumed; H may overwrite its base

    // ---- H write (aliased into st) ----
#pragma unroll
    for (int k6 = 0; k6 < 6; ++k6) {
        const int t = wv + 8 * k6;
        const int xs = t & 3, yt = t >> 2;
        const int n = 16 * yt + m16;
#pragma unroll
        for (int q = 0; q < 4; ++q)
            Hl[(16 * xs + 4 * g + q) * YP + n] = f2bf(cacc[k6][q]);
    }
    __syncthreads();

    // ---- phase D: vblur + fused epilogue, 32 tiles (4 x 8), 4/wave ----
#pragma unroll
    for (int k4 = 0; k4 < 4; ++k4) {
        const int t = wv + 8 * k4;
        const int xs2 = t & 3, ys = t >> 2;
        const int xl = 16 * xs2 + m16;
        f32x4 acc = {0.f, 0.f, 0.f, 0.f};
#pragma unroll
        for (int rs = 0; rs < 2; ++rs) {
            const bf16x8 b = *(const bf16x8*)&Hl[xl * YP + 16 * ys + 8 + 32 * rs + 8 * g];
            acc = __builtin_amdgcn_mfma_f32_16x16x32_bf16(a_v[rs], b, acc, 0, 0, 0);
        }
        if (g == 3) {
            const float h72 = bf2f(Hl[xl * YP + 16 * ys + 72]);
            const float h73 = bf2f(Hl[xl * YP + 16 * ys + 73]);
            acc[2] = fmaf(gg50, h72, acc[2]);                   // i=14, t=50
            acc[3] = fmaf(gg49, h72, fmaf(gg50, h73, acc[3]));  // i=15, t=49,50
        }
        const int yl0 = 16 * ys + 4 * g;
#pragma unroll
        for (int q = 0; q < 4; ++q) {
            const int di = (y0 + yl0 + q) * IMG + (x0 + xl);
            if (PASS == 0) {
                const float iv = bf2f(civ[k4][q]);   // staged img center, no global read
                resb[di] = f2bf(iv - acc[q]);
            } else {
                const float iv = imgb[di];           // L2-hot (tile just staged)
                const float rv = bf2f(resb[di]);
                float sharp = fmaf(0.5f, rv, iv);
                sharp = fminf(fmaxf(sharp, 0.f), 1.f);
                outb[di] = fmaf(acc[q], sharp - iv, iv);  // img + sm*(sharp-img)
            }
        }
    }
}

extern "C" void kernel_launch(void* const* d_in, const int* in_sizes, int n_in,
                              void* d_out, int out_size, void* d_ws, size_t ws_size,
                              hipStream_t stream) {
    (void)in_sizes; (void)n_in; (void)out_size; (void)ws_size;
    const float* img = (const float*)d_in[0];
    const float* k1d = (const float*)d_in[1];
    float* out = (float*)d_out;
    unsigned short* rs = (unsigned short*)d_ws;  // 25165824 B

    const dim3 grid(NIMG * 32);  // 1536 blocks x 512 threads

    usm_kern<0><<<grid, 512, 0, stream>>>(img, rs, out, k1d);
    usm_kern<1><<<grid, 512, 0, stream>>>(img, rs, out, k1d);
}